// Round 1
// baseline (244.384 us; speedup 1.0000x reference)
//
#include <hip/hip_runtime.h>
#include <hip/hip_bf16.h>

// Fused pre-LN MHA block: LN -> QKV GEMM -> flash attn -> out-proj + residual.
// All matmuls bf16 MFMA (16x16x32), fp32 accumulate.
//
// Workspace layout (48 MB total):
//   [ 0MB) h      bf16 [4096,1024]
//   [ 8MB) WqkvT  bf16 [3072,1024]
//   [14MB) WoutT  bf16 [1024,1024]
//   [16MB) q      bf16 [B,H,T,64]  (pre-scaled by 1/8)
//   [24MB) k      bf16 [B,H,T,64]
//   [32MB) vT     bf16 [B,H,64,T]
//   [40MB) attno  bf16 [4096,1024]

#define DINL static __device__ __forceinline__

typedef __attribute__((ext_vector_type(8))) short bf16x8;
typedef __attribute__((ext_vector_type(4))) float f32x4;

DINL unsigned short f2bf(float f) {
  __hip_bfloat16 h = __float2bfloat16(f);
  unsigned short u;
  __builtin_memcpy(&u, &h, 2);
  return u;
}

DINL void gload_lds16(const void* g, void* l) {
  // 16B per lane; LDS dest = wave-uniform base + lane*16
  __builtin_amdgcn_global_load_lds((__attribute__((address_space(1))) void*)g,
                                   (__attribute__((address_space(3))) void*)l,
                                   16, 0, 0);
}

// ---------------- LayerNorm (fp32 -> bf16) ----------------
__global__ __launch_bounds__(256)
void ln_kernel(const float* __restrict__ x, const float* __restrict__ gamma,
               const float* __restrict__ beta, unsigned short* __restrict__ h) {
  __shared__ float red[8];
  int row = blockIdx.x;          // 0..4095
  int t = threadIdx.x;           // 0..255, 4 floats each
  float4 v = reinterpret_cast<const float4*>(x + (size_t)row * 1024)[t];
  float s  = v.x + v.y + v.z + v.w;
  float sq = v.x*v.x + v.y*v.y + v.z*v.z + v.w*v.w;
#pragma unroll
  for (int off = 1; off < 64; off <<= 1) {
    s  += __shfl_xor(s, off);
    sq += __shfl_xor(sq, off);
  }
  int wid = t >> 6;
  if ((t & 63) == 0) { red[wid] = s; red[4 + wid] = sq; }
  __syncthreads();
  s  = red[0] + red[1] + red[2] + red[3];
  sq = red[4] + red[5] + red[6] + red[7];
  float mu   = s * (1.0f / 1024.0f);
  float var  = sq * (1.0f / 1024.0f) - mu * mu;
  float rstd = rsqrtf(var + 1e-5f);
  float4 g = reinterpret_cast<const float4*>(gamma)[t];
  float4 b = reinterpret_cast<const float4*>(beta)[t];
  ushort4 o;
  o.x = f2bf((v.x - mu) * rstd * g.x + b.x);
  o.y = f2bf((v.y - mu) * rstd * g.y + b.y);
  o.z = f2bf((v.z - mu) * rstd * g.z + b.z);
  o.w = f2bf((v.w - mu) * rstd * g.w + b.w);
  reinterpret_cast<ushort4*>(h + (size_t)row * 1024)[t] = o;
}

// ---------------- Transpose + cast: src fp32 [R,C] -> dst bf16 [C,R] ----------------
__global__ __launch_bounds__(256)
void transpose_cast_kernel(const float* __restrict__ src, unsigned short* __restrict__ dst,
                           int R, int C) {
  __shared__ float tile[32][33];
  int tx = threadIdx.x & 31, ty = threadIdx.x >> 5;  // 32 x 8
  int c0 = blockIdx.x * 32, r0 = blockIdx.y * 32;
#pragma unroll
  for (int i = 0; i < 4; i++)
    tile[ty + i * 8][tx] = src[(size_t)(r0 + ty + i * 8) * C + c0 + tx];
  __syncthreads();
#pragma unroll
  for (int i = 0; i < 4; i++) {
    int r = ty + i * 8;
    dst[(size_t)(c0 + r) * R + r0 + tx] = f2bf(tile[tx][r]);
  }
}

// ---------------- GEMM: C[M,N] = A[M,K] * Bt[N,K]^T (+epilogue) ----------------
// 128x128 tile, BK=64, 256 threads = 4 waves (2x2 of 64x64), 16x16x32 MFMA.
// LDS kb-major: chunk c = kb*128 + row holds 8 bf16 of row `row`, k-slice kb.
// MODE 0: qkv epilogue (bias, split q/k/vT, q scaled). MODE 1: bias+residual fp32 out.
template <int MODE>
__global__ __launch_bounds__(256)
void gemm128(const unsigned short* __restrict__ A,
             const unsigned short* __restrict__ Bt,
             int K,
             const float* __restrict__ bias,
             unsigned short* __restrict__ qdst, unsigned short* __restrict__ kdst,
             unsigned short* __restrict__ vTdst,
             const float* __restrict__ xres, float* __restrict__ out) {
  __shared__ unsigned short As[8192];  // 16 KB
  __shared__ unsigned short Bs[8192];
  int tid = threadIdx.x, wid = tid >> 6, lane = tid & 63;
  int l15 = lane & 15, l4 = lane >> 4;
  int brow = blockIdx.y * 128, bcol = blockIdx.x * 128;
  int wr = wid >> 1, wc = wid & 1;
  f32x4 acc[4][4] = {};

  for (int kt = 0; kt < K; kt += 64) {
    __syncthreads();
#pragma unroll
    for (int r = 0; r < 4; r++) {
      int c  = wid * 256 + r * 64;   // wave-uniform chunk base
      int cl = c + lane;
      int kb = cl >> 7, row = cl & 127;
      gload_lds16(A  + (size_t)(brow + row) * K + kt + kb * 8, As + c * 8);
      gload_lds16(Bt + (size_t)(bcol + row) * K + kt + kb * 8, Bs + c * 8);
    }
    __syncthreads();
#pragma unroll
    for (int ks = 0; ks < 2; ks++) {
      int kb = ks * 4 + l4;
      bf16x8 af[4], bfr[4];
#pragma unroll
      for (int m = 0; m < 4; m++)
        af[m] = *reinterpret_cast<const bf16x8*>(As + (kb * 128 + wr * 64 + m * 16 + l15) * 8);
#pragma unroll
      for (int n = 0; n < 4; n++)
        bfr[n] = *reinterpret_cast<const bf16x8*>(Bs + (kb * 128 + wc * 64 + n * 16 + l15) * 8);
#pragma unroll
      for (int m = 0; m < 4; m++)
#pragma unroll
        for (int n = 0; n < 4; n++)
          acc[m][n] = __builtin_amdgcn_mfma_f32_16x16x32_bf16(af[m], bfr[n], acc[m][n], 0, 0, 0);
    }
  }

  if (MODE == 0) {
    int sec = bcol >> 10;            // 0=q, 1=k, 2=v  (128-wide tiles never straddle)
    int secbase = sec << 10;
#pragma unroll
    for (int m = 0; m < 4; m++) {
      int row0 = brow + wr * 64 + m * 16 + l4 * 4;
      int b = row0 >> 11, t0 = row0 & 2047;
#pragma unroll
      for (int n = 0; n < 4; n++) {
        int col = (bcol & 1023) + wc * 64 + n * 16 + l15;
        float bv = bias[secbase + col];
        int hh = col >> 6, d = col & 63;
        if (sec == 2) {
          ushort4 pk;
          pk.x = f2bf(acc[m][n][0] + bv);
          pk.y = f2bf(acc[m][n][1] + bv);
          pk.z = f2bf(acc[m][n][2] + bv);
          pk.w = f2bf(acc[m][n][3] + bv);
          *reinterpret_cast<ushort4*>(vTdst + ((size_t)(b * 16 + hh) * 64 + d) * 2048 + t0) = pk;
        } else {
          unsigned short* dst = (sec == 0) ? qdst : kdst;
          float sc = (sec == 0) ? 0.125f : 1.0f;
#pragma unroll
          for (int j = 0; j < 4; j++)
            dst[((size_t)(b * 16 + hh) * 2048 + t0 + j) * 64 + d] = f2bf((acc[m][n][j] + bv) * sc);
        }
      }
    }
  } else {
#pragma unroll
    for (int m = 0; m < 4; m++) {
      int row0 = brow + wr * 64 + m * 16 + l4 * 4;
#pragma unroll
      for (int n = 0; n < 4; n++) {
        int col = bcol + wc * 64 + n * 16 + l15;
        float bv = bias[col];
#pragma unroll
        for (int j = 0; j < 4; j++) {
          size_t idx = (size_t)(row0 + j) * 1024 + col;
          out[idx] = acc[m][n][j] + bv + xres[idx];
        }
      }
    }
  }
}

// ---------------- Flash attention ----------------
// Grid: (T/128, B*H). 4 waves x 32 q-rows. KV tiles of 64.
__global__ __launch_bounds__(256)
void attn_kernel(const unsigned short* __restrict__ q,
                 const unsigned short* __restrict__ kk,
                 const unsigned short* __restrict__ vT,
                 unsigned short* __restrict__ o) {
  const int T = 2048;
  __shared__ unsigned short Ks[4096];       // kb(8) x key(64) x 8 = 8 KB
  __shared__ unsigned short Vs[4096];       // kb(8) x d(64) x 8   = 8 KB
  __shared__ unsigned short Ps[4][32][72];  // per-wave P, stride 144B (16B-aligned)
  int tid = threadIdx.x, wid = tid >> 6, lane = tid & 63;
  int l15 = lane & 15, l4 = lane >> 4;
  int bh = blockIdx.y;
  int q0 = blockIdx.x * 128;
  const unsigned short* qh = q  + (size_t)bh * T * 64;
  const unsigned short* kh = kk + (size_t)bh * T * 64;
  const unsigned short* vh = vT + (size_t)bh * 64 * T;

  bf16x8 qf[2][2];
#pragma unroll
  for (int m = 0; m < 2; m++)
#pragma unroll
    for (int ks = 0; ks < 2; ks++)
      qf[m][ks] = *reinterpret_cast<const bf16x8*>(
          qh + (size_t)(q0 + wid * 32 + m * 16 + l15) * 64 + ks * 32 + l4 * 8);

  f32x4 accO[2][4] = {};
  float mst[2][4], lst[2][4];
#pragma unroll
  for (int m = 0; m < 2; m++)
#pragma unroll
    for (int j = 0; j < 4; j++) { mst[m][j] = -1e30f; lst[m][j] = 0.0f; }

  for (int kv0 = 0; kv0 < T; kv0 += 64) {
    __syncthreads();
#pragma unroll
    for (int r = 0; r < 2; r++) {
      int c  = wid * 128 + r * 64;
      int cl = c + lane;
      int kb = cl >> 6, key = cl & 63;    // key doubles as d for V
      gload_lds16(kh + (size_t)(kv0 + key) * 64 + kb * 8, Ks + c * 8);
      gload_lds16(vh + (size_t)key * T + kv0 + kb * 8,    Vs + c * 8);
    }
    __syncthreads();

    // S = Q K^T  (C-layout: lane holds S[q=(l>>4)*4+j + m*16][key=n*16+(l&15)])
    f32x4 s[2][4] = {};
#pragma unroll
    for (int ks = 0; ks < 2; ks++) {
      int kb = ks * 4 + l4;
      bf16x8 kf[4];
#pragma unroll
      for (int n = 0; n < 4; n++)
        kf[n] = *reinterpret_cast<const bf16x8*>(Ks + (kb * 64 + n * 16 + l15) * 8);
#pragma unroll
      for (int m = 0; m < 2; m++)
#pragma unroll
        for (int n = 0; n < 4; n++)
          s[m][n] = __builtin_amdgcn_mfma_f32_16x16x32_bf16(qf[m][ks], kf[n], s[m][n], 0, 0, 0);
    }

    // online softmax (row spread over 16 lanes x 4 n-frags)
    float al[2][4];
#pragma unroll
    for (int m = 0; m < 2; m++)
#pragma unroll
      for (int j = 0; j < 4; j++) {
        float mx = s[m][0][j];
#pragma unroll
        for (int n = 1; n < 4; n++) mx = fmaxf(mx, s[m][n][j]);
#pragma unroll
        for (int xm = 1; xm < 16; xm <<= 1) mx = fmaxf(mx, __shfl_xor(mx, xm));
        float mnew = fmaxf(mst[m][j], mx);
        float a = __expf(mst[m][j] - mnew);
        float sum = 0.0f;
#pragma unroll
        for (int n = 0; n < 4; n++) {
          float p = __expf(s[m][n][j] - mnew);
          s[m][n][j] = p;
          sum += p;
        }
#pragma unroll
        for (int xm = 1; xm < 16; xm <<= 1) sum += __shfl_xor(sum, xm);
        lst[m][j] = lst[m][j] * a + sum;
        mst[m][j] = mnew;
        al[m][j] = a;
      }
#pragma unroll
    for (int m = 0; m < 2; m++)
#pragma unroll
      for (int n = 0; n < 4; n++)
#pragma unroll
        for (int j = 0; j < 4; j++) accO[m][n][j] *= al[m][j];

    // P (C-layout) -> bf16 -> wave-private LDS -> A-fragments
#pragma unroll
    for (int m = 0; m < 2; m++)
#pragma unroll
      for (int n = 0; n < 4; n++) {
        int key = n * 16 + l15;
#pragma unroll
        for (int j = 0; j < 4; j++)
          Ps[wid][m * 16 + l4 * 4 + j][key] = f2bf(s[m][n][j]);
      }
    // PV (wave-private Ps: compiler orders ds_write->ds_read via lgkmcnt)
#pragma unroll
    for (int ks = 0; ks < 2; ks++) {
      int kb = ks * 4 + l4;
      bf16x8 pf[2], vf[4];
#pragma unroll
      for (int m = 0; m < 2; m++)
        pf[m] = *reinterpret_cast<const bf16x8*>(&Ps[wid][m * 16 + l15][ks * 32 + l4 * 8]);
#pragma unroll
      for (int n = 0; n < 4; n++)
        vf[n] = *reinterpret_cast<const bf16x8*>(Vs + (kb * 64 + n * 16 + l15) * 8);
#pragma unroll
      for (int m = 0; m < 2; m++)
#pragma unroll
        for (int n = 0; n < 4; n++)
          accO[m][n] = __builtin_amdgcn_mfma_f32_16x16x32_bf16(pf[m], vf[n], accO[m][n], 0, 0, 0);
    }
  }

  int b = bh >> 4, hh = bh & 15;
#pragma unroll
  for (int m = 0; m < 2; m++)
#pragma unroll
    for (int n = 0; n < 4; n++)
#pragma unroll
      for (int j = 0; j < 4; j++) {
        int trow = q0 + wid * 32 + m * 16 + l4 * 4 + j;
        int d = n * 16 + l15;
        o[(size_t)(b * 2048 + trow) * 1024 + hh * 64 + d] = f2bf(accO[m][n][j] / lst[m][j]);
      }
}

extern "C" void kernel_launch(void* const* d_in, const int* in_sizes, int n_in,
                              void* d_out, int out_size, void* d_ws, size_t ws_size,
                              hipStream_t stream) {
  const float* x     = (const float*)d_in[0];
  const float* W_qkv = (const float*)d_in[1];
  const float* b_qkv = (const float*)d_in[2];
  const float* W_out = (const float*)d_in[3];
  const float* b_out = (const float*)d_in[4];
  const float* gamma = (const float*)d_in[5];
  const float* beta  = (const float*)d_in[6];
  float* out = (float*)d_out;

  char* ws = (char*)d_ws;
  unsigned short* h     = (unsigned short*)(ws);
  unsigned short* WqkvT = (unsigned short*)(ws + (size_t)(8)  * 1024 * 1024);
  unsigned short* WoutT = (unsigned short*)(ws + (size_t)(14) * 1024 * 1024);
  unsigned short* qb    = (unsigned short*)(ws + (size_t)(16) * 1024 * 1024);
  unsigned short* kb    = (unsigned short*)(ws + (size_t)(24) * 1024 * 1024);
  unsigned short* vTb   = (unsigned short*)(ws + (size_t)(32) * 1024 * 1024);
  unsigned short* attno = (unsigned short*)(ws + (size_t)(40) * 1024 * 1024);

  ln_kernel<<<4096, 256, 0, stream>>>(x, gamma, beta, h);
  transpose_cast_kernel<<<dim3(96, 32), 256, 0, stream>>>(W_qkv, WqkvT, 1024, 3072);
  transpose_cast_kernel<<<dim3(32, 32), 256, 0, stream>>>(W_out, WoutT, 1024, 1024);
  gemm128<0><<<dim3(24, 32), 256, 0, stream>>>(h, WqkvT, 1024, b_qkv, qb, kb, vTb, nullptr, nullptr);
  attn_kernel<<<dim3(16, 32), 256, 0, stream>>>(qb, kb, vTb, attno);
  gemm128<1><<<dim3(8, 32), 256, 0, stream>>>(attno, WoutT, 1024, b_out, nullptr, nullptr, nullptr, x, out);
}

// Round 3
// 211.079 us; speedup vs baseline: 1.1578x; 1.1578x over previous
//
#include <hip/hip_runtime.h>
#include <hip/hip_bf16.h>

// Fused pre-LN MHA block: LN -> QKV GEMM -> flash attn -> out-proj + residual.
// All matmuls bf16 MFMA (16x16x32), fp32 accumulate.
//
// Workspace layout (48 MB total):
//   [ 0MB) h      bf16 [4096,1024]
//   [ 8MB) WqkvT  bf16 [3072,1024]
//   [14MB) WoutT  bf16 [1024,1024]
//   [16MB) q      bf16 [B,H,T,64]  (pre-scaled by 0.125*log2e; softmax uses exp2)
//   [24MB) k      bf16 [B,H,T,64]
//   [32MB) vT     bf16 [B,H,64,T]
//   [40MB) attno  bf16 [4096,1024]

#define DINL static __device__ __forceinline__

typedef __attribute__((ext_vector_type(8))) short bf16x8;
typedef __attribute__((ext_vector_type(4))) float f32x4;

DINL float fast_exp2(float x) { return __builtin_amdgcn_exp2f(x); }

DINL unsigned short f2bf(float f) {
  __hip_bfloat16 h = __float2bfloat16(f);
  unsigned short u;
  __builtin_memcpy(&u, &h, 2);
  return u;
}

// cheap round-half-up f32->bf16 (abs err <= 1 ulp; fine at 0.1 threshold)
DINL unsigned short f2bf_fast(float f) {
  unsigned int u;
  __builtin_memcpy(&u, &f, 4);
  return (unsigned short)((u + 0x8000u) >> 16);
}

DINL void gload_lds16(const void* g, void* l) {
  // 16B per lane; LDS dest = wave-uniform base + lane*16
  __builtin_amdgcn_global_load_lds((__attribute__((address_space(1))) void*)g,
                                   (__attribute__((address_space(3))) void*)l,
                                   16, 0, 0);
}

// ---------------- LayerNorm (fp32 -> bf16) ----------------
__global__ __launch_bounds__(256)
void ln_kernel(const float* __restrict__ x, const float* __restrict__ gamma,
               const float* __restrict__ beta, unsigned short* __restrict__ h) {
  __shared__ float red[8];
  int row = blockIdx.x;          // 0..4095
  int t = threadIdx.x;           // 0..255, 4 floats each
  float4 v = reinterpret_cast<const float4*>(x + (size_t)row * 1024)[t];
  float s  = v.x + v.y + v.z + v.w;
  float sq = v.x*v.x + v.y*v.y + v.z*v.z + v.w*v.w;
#pragma unroll
  for (int off = 1; off < 64; off <<= 1) {
    s  += __shfl_xor(s, off);
    sq += __shfl_xor(sq, off);
  }
  int wid = t >> 6;
  if ((t & 63) == 0) { red[wid] = s; red[4 + wid] = sq; }
  __syncthreads();
  s  = red[0] + red[1] + red[2] + red[3];
  sq = red[4] + red[5] + red[6] + red[7];
  float mu   = s * (1.0f / 1024.0f);
  float var  = sq * (1.0f / 1024.0f) - mu * mu;
  float rstd = rsqrtf(var + 1e-5f);
  float4 g = reinterpret_cast<const float4*>(gamma)[t];
  float4 b = reinterpret_cast<const float4*>(beta)[t];
  ushort4 o;
  o.x = f2bf((v.x - mu) * rstd * g.x + b.x);
  o.y = f2bf((v.y - mu) * rstd * g.y + b.y);
  o.z = f2bf((v.z - mu) * rstd * g.z + b.z);
  o.w = f2bf((v.w - mu) * rstd * g.w + b.w);
  reinterpret_cast<ushort4*>(h + (size_t)row * 1024)[t] = o;
}

// ---------------- Transpose + cast: src fp32 [R,C] -> dst bf16 [C,R] ----------------
__global__ __launch_bounds__(256)
void transpose_cast_kernel(const float* __restrict__ src, unsigned short* __restrict__ dst,
                           int R, int C) {
  __shared__ float tile[32][33];
  int tx = threadIdx.x & 31, ty = threadIdx.x >> 5;  // 32 x 8
  int c0 = blockIdx.x * 32, r0 = blockIdx.y * 32;
#pragma unroll
  for (int i = 0; i < 4; i++)
    tile[ty + i * 8][tx] = src[(size_t)(r0 + ty + i * 8) * C + c0 + tx];
  __syncthreads();
#pragma unroll
  for (int i = 0; i < 4; i++) {
    int r = ty + i * 8;
    dst[(size_t)(c0 + r) * R + r0 + tx] = f2bf(tile[tx][r]);
  }
}

// ---------------- GEMM: C[M,N] = A[M,K] * Bt[N,K]^T (+epilogue) ----------------
// 128x128 tile, BK=64, 256 threads = 4 waves (2x2 of 64x64), 16x16x32 MFMA.
// LDS kb-major: chunk c = kb*128 + row holds 8 bf16 of row `row`, k-slice kb.
// MODE 0: qkv epilogue (bias, split q/k/vT, q scaled). MODE 1: bias+residual fp32 out.
template <int MODE>
__global__ __launch_bounds__(256)
void gemm128(const unsigned short* __restrict__ A,
             const unsigned short* __restrict__ Bt,
             int K,
             const float* __restrict__ bias,
             unsigned short* __restrict__ qdst, unsigned short* __restrict__ kdst,
             unsigned short* __restrict__ vTdst,
             const float* __restrict__ xres, float* __restrict__ out) {
  __shared__ unsigned short As[8192];  // 16 KB
  __shared__ unsigned short Bs[8192];
  int tid = threadIdx.x, wid = tid >> 6, lane = tid & 63;
  int l15 = lane & 15, l4 = lane >> 4;
  int brow = blockIdx.y * 128, bcol = blockIdx.x * 128;
  int wr = wid >> 1, wc = wid & 1;
  f32x4 acc[4][4] = {};

  for (int kt = 0; kt < K; kt += 64) {
    __syncthreads();
#pragma unroll
    for (int r = 0; r < 4; r++) {
      int c  = wid * 256 + r * 64;   // wave-uniform chunk base
      int cl = c + lane;
      int kb = cl >> 7, row = cl & 127;
      gload_lds16(A  + (size_t)(brow + row) * K + kt + kb * 8, As + c * 8);
      gload_lds16(Bt + (size_t)(bcol + row) * K + kt + kb * 8, Bs + c * 8);
    }
    __syncthreads();
#pragma unroll
    for (int ks = 0; ks < 2; ks++) {
      int kb = ks * 4 + l4;
      bf16x8 af[4], bfr[4];
#pragma unroll
      for (int m = 0; m < 4; m++)
        af[m] = *reinterpret_cast<const bf16x8*>(As + (kb * 128 + wr * 64 + m * 16 + l15) * 8);
#pragma unroll
      for (int n = 0; n < 4; n++)
        bfr[n] = *reinterpret_cast<const bf16x8*>(Bs + (kb * 128 + wc * 64 + n * 16 + l15) * 8);
#pragma unroll
      for (int m = 0; m < 4; m++)
#pragma unroll
        for (int n = 0; n < 4; n++)
          acc[m][n] = __builtin_amdgcn_mfma_f32_16x16x32_bf16(af[m], bfr[n], acc[m][n], 0, 0, 0);
    }
  }

  if (MODE == 0) {
    int sec = bcol >> 10;            // 0=q, 1=k, 2=v  (128-wide tiles never straddle)
    int secbase = sec << 10;
#pragma unroll
    for (int m = 0; m < 4; m++) {
      int row0 = brow + wr * 64 + m * 16 + l4 * 4;
      int b = row0 >> 11, t0 = row0 & 2047;
#pragma unroll
      for (int n = 0; n < 4; n++) {
        int col = (bcol & 1023) + wc * 64 + n * 16 + l15;
        float bv = bias[secbase + col];
        int hh = col >> 6, d = col & 63;
        if (sec == 2) {
          ushort4 pk;
          pk.x = f2bf(acc[m][n][0] + bv);
          pk.y = f2bf(acc[m][n][1] + bv);
          pk.z = f2bf(acc[m][n][2] + bv);
          pk.w = f2bf(acc[m][n][3] + bv);
          *reinterpret_cast<ushort4*>(vTdst + ((size_t)(b * 16 + hh) * 64 + d) * 2048 + t0) = pk;
        } else {
          unsigned short* dst = (sec == 0) ? qdst : kdst;
          // q pre-scaled by 1/sqrt(hd) * log2(e) so attention can use exp2
          float sc = (sec == 0) ? 0.125f * 1.44269504088896f : 1.0f;
#pragma unroll
          for (int j = 0; j < 4; j++)
            dst[((size_t)(b * 16 + hh) * 2048 + t0 + j) * 64 + d] = f2bf((acc[m][n][j] + bv) * sc);
        }
      }
    }
  } else {
#pragma unroll
    for (int m = 0; m < 4; m++) {
      int row0 = brow + wr * 64 + m * 16 + l4 * 4;
#pragma unroll
      for (int n = 0; n < 4; n++) {
        int col = bcol + wc * 64 + n * 16 + l15;
        float bv = bias[col];
#pragma unroll
        for (int j = 0; j < 4; j++) {
          size_t idx = (size_t)(row0 + j) * 1024 + col;
          out[idx] = acc[m][n][j] + bv + xres[idx];
        }
      }
    }
  }
}

// ---------------- Flash attention ----------------
// Grid: (T/64, B*H). 4 waves x 16 q-rows each. KV tiles of 64, double-buffered.
// LDS key-major + XOR swizzle: 16B slot s holds chunk(key=s>>3, kb=(s&7)^((s>>3)&7)).
// Staging pre-swizzles the GLOBAL source so global_load_lds stays linear (m173).
__global__ __launch_bounds__(256, 4)
void attn_kernel(const unsigned short* __restrict__ q,
                 const unsigned short* __restrict__ kk,
                 const unsigned short* __restrict__ vT,
                 unsigned short* __restrict__ o) {
  const int T = 2048;
  __shared__ unsigned short Ks[2][4096];   // 16 KB
  __shared__ unsigned short Vs[2][4096];   // 16 KB
  __shared__ unsigned short Ps[4][1024];   // 8 KB, per-wave, swizzled idx^=((row&7)<<3)
  int tid = threadIdx.x, wid = tid >> 6, lane = tid & 63;
  int l15 = lane & 15, l4 = lane >> 4;
  int bh = blockIdx.y;
  int q0 = blockIdx.x * 64 + wid * 16;     // wave's 16 q-rows
  const unsigned short* qh = q  + (size_t)bh * T * 64;
  const unsigned short* kh = kk + (size_t)bh * T * 64;
  const unsigned short* vh = vT + (size_t)bh * 64 * T;

  bf16x8 qf[2];
#pragma unroll
  for (int ks = 0; ks < 2; ks++)
    qf[ks] = *reinterpret_cast<const bf16x8*>(
        qh + (size_t)(q0 + l15) * 64 + ks * 32 + l4 * 8);

  f32x4 accO[4] = {};
  float mst[4], lst[4];
#pragma unroll
  for (int j = 0; j < 4; j++) { mst[j] = -1e30f; lst[j] = 0.0f; }

  // stage one KV tile (coalesced: 8-lane groups read 128B rows, kb pre-swizzled)
#define STAGE(buf, kv0)                                                        \
  {                                                                            \
    _Pragma("unroll") for (int r = 0; r < 2; r++) {                            \
      int c  = (wid * 2 + r) * 64;                                             \
      int sl = c + lane;                                                       \
      int key = sl >> 3;                                                       \
      int kb  = (sl & 7) ^ (key & 7);                                          \
      gload_lds16(kh + (size_t)((kv0) + key) * 64 + kb * 8, &Ks[buf][c * 8]);  \
      gload_lds16(vh + (size_t)key * T + (kv0) + kb * 8,    &Vs[buf][c * 8]);  \
    }                                                                          \
  }

  STAGE(0, 0);
  __syncthreads();
  int cur = 0;

  for (int kv0 = 0; kv0 < T; kv0 += 64) {
    if (kv0 + 64 < T) STAGE(cur ^ 1, kv0 + 64);

    // S = Q K^T  (C-layout: lane holds S[q=l4*4+j][key=n*16+l15])
    f32x4 s[4] = {};
#pragma unroll
    for (int ks = 0; ks < 2; ks++) {
      int kbase = (ks * 4 + l4);
#pragma unroll
      for (int n = 0; n < 4; n++) {
        int slot = (n * 16 + l15) * 8 + (kbase ^ (l15 & 7));
        bf16x8 kf = *reinterpret_cast<const bf16x8*>(&Ks[cur][slot * 8]);
        s[n] = __builtin_amdgcn_mfma_f32_16x16x32_bf16(qf[ks], kf, s[n], 0, 0, 0);
      }
    }

    // online softmax in log2 domain (q pre-scaled by log2e)
    float al[4];
#pragma unroll
    for (int j = 0; j < 4; j++) {
      float mx = fmaxf(fmaxf(s[0][j], s[1][j]), fmaxf(s[2][j], s[3][j]));
#pragma unroll
      for (int xm = 1; xm < 16; xm <<= 1) mx = fmaxf(mx, __shfl_xor(mx, xm));
      float mnew = fmaxf(mst[j], mx);
      float a = fast_exp2(mst[j] - mnew);
      float sum = 0.0f;
#pragma unroll
      for (int n = 0; n < 4; n++) {
        float p = fast_exp2(s[n][j] - mnew);
        s[n][j] = p;
        sum += p;
      }
#pragma unroll
      for (int xm = 1; xm < 16; xm <<= 1) sum += __shfl_xor(sum, xm);
      lst[j] = lst[j] * a + sum;
      mst[j] = mnew;
      al[j] = a;
    }
#pragma unroll
    for (int n = 0; n < 4; n++)
#pragma unroll
      for (int j = 0; j < 4; j++) accO[n][j] *= al[j];

    // P (C-layout) -> bf16 -> wave-private swizzled LDS
#pragma unroll
    for (int n = 0; n < 4; n++) {
      int col = n * 16 + l15;
#pragma unroll
      for (int j = 0; j < 4; j++) {
        int row = l4 * 4 + j;
        Ps[wid][row * 64 + (col ^ ((row & 7) << 3))] = f2bf_fast(s[n][j]);
      }
    }
    // PV: A = P rows l15, k = keys; B = V^T cols d
#pragma unroll
    for (int ks = 0; ks < 2; ks++) {
      bf16x8 pf = *reinterpret_cast<const bf16x8*>(
          &Ps[wid][l15 * 64 + ((ks * 32 + l4 * 8) ^ ((l15 & 7) << 3))]);
      int kbase = (ks * 4 + l4);
#pragma unroll
      for (int n = 0; n < 4; n++) {
        int slot = (n * 16 + l15) * 8 + (kbase ^ (l15 & 7));
        bf16x8 vf = *reinterpret_cast<const bf16x8*>(&Vs[cur][slot * 8]);
        accO[n] = __builtin_amdgcn_mfma_f32_16x16x32_bf16(pf, vf, accO[n], 0, 0, 0);
      }
    }

    __syncthreads();   // drains prefetch vmcnt + all waves done with buf[cur]
    cur ^= 1;
  }
#undef STAGE

  int b = bh >> 4, hh = bh & 15;
#pragma unroll
  for (int j = 0; j < 4; j++) {
    float inv = 1.0f / lst[j];
    int trow = q0 + l4 * 4 + j;
#pragma unroll
    for (int n = 0; n < 4; n++) {
      int d = n * 16 + l15;
      o[(size_t)(b * 2048 + trow) * 1024 + hh * 64 + d] = f2bf(accO[n][j] * inv);
    }
  }
}

extern "C" void kernel_launch(void* const* d_in, const int* in_sizes, int n_in,
                              void* d_out, int out_size, void* d_ws, size_t ws_size,
                              hipStream_t stream) {
  const float* x     = (const float*)d_in[0];
  const float* W_qkv = (const float*)d_in[1];
  const float* b_qkv = (const float*)d_in[2];
  const float* W_out = (const float*)d_in[3];
  const float* b_out = (const float*)d_in[4];
  const float* gamma = (const float*)d_in[5];
  const float* beta  = (const float*)d_in[6];
  float* out = (float*)d_out;

  char* ws = (char*)d_ws;
  unsigned short* h     = (unsigned short*)(ws);
  unsigned short* WqkvT = (unsigned short*)(ws + (size_t)(8)  * 1024 * 1024);
  unsigned short* WoutT = (unsigned short*)(ws + (size_t)(14) * 1024 * 1024);
  unsigned short* qb    = (unsigned short*)(ws + (size_t)(16) * 1024 * 1024);
  unsigned short* kb    = (unsigned short*)(ws + (size_t)(24) * 1024 * 1024);
  unsigned short* vTb   = (unsigned short*)(ws + (size_t)(32) * 1024 * 1024);
  unsigned short* attno = (unsigned short*)(ws + (size_t)(40) * 1024 * 1024);

  ln_kernel<<<4096, 256, 0, stream>>>(x, gamma, beta, h);
  transpose_cast_kernel<<<dim3(96, 32), 256, 0, stream>>>(W_qkv, WqkvT, 1024, 3072);
  transpose_cast_kernel<<<dim3(32, 32), 256, 0, stream>>>(W_out, WoutT, 1024, 1024);
  gemm128<0><<<dim3(24, 32), 256, 0, stream>>>(h, WqkvT, 1024, b_qkv, qb, kb, vTb, nullptr, nullptr);
  attn_kernel<<<dim3(32, 32), 256, 0, stream>>>(qb, kb, vTb, attno);
  gemm128<1><<<dim3(8, 32), 256, 0, stream>>>(attno, WoutT, 1024, b_out, nullptr, nullptr, nullptr, x, out);
}

// Round 4
// 195.584 us; speedup vs baseline: 1.2495x; 1.0792x over previous
//
#include <hip/hip_runtime.h>
#include <hip/hip_bf16.h>

// Fused pre-LN MHA block: LN -> QKV GEMM -> flash attn -> out-proj + residual.
// All matmuls bf16 MFMA (16x16x32), fp32 accumulate.
//
// Workspace layout (48 MB total):
//   [ 0MB) h      bf16 [4096,1024]
//   [ 8MB) WqkvT  bf16 [3072,1024]
//   [14MB) WoutT  bf16 [1024,1024]
//   [16MB) q      bf16 [B,H,T,64]  (pre-scaled by 0.125*log2e; softmax uses exp2)
//   [24MB) k      bf16 [B,H,T,64]
//   [32MB) vT     bf16 [B,H,64,T]
//   [40MB) attno  bf16 [4096,1024]

#define DINL static __device__ __forceinline__

typedef __attribute__((ext_vector_type(8))) short bf16x8;
typedef __attribute__((ext_vector_type(4))) float f32x4;

DINL float fast_exp2(float x) { return __builtin_amdgcn_exp2f(x); }

DINL unsigned short f2bf(float f) {
  __hip_bfloat16 h = __float2bfloat16(f);
  unsigned short u;
  __builtin_memcpy(&u, &h, 2);
  return u;
}

// cheap round-half-up f32->bf16 (abs err <= 1 ulp; fine at 0.1 threshold)
DINL unsigned int bfbits(float f) {
  unsigned int u;
  __builtin_memcpy(&u, &f, 4);
  return (u + 0x8000u) >> 16;
}

DINL void gload_lds16(const void* g, void* l) {
  // 16B per lane; LDS dest = wave-uniform base + lane*16
  __builtin_amdgcn_global_load_lds((__attribute__((address_space(1))) void*)g,
                                   (__attribute__((address_space(3))) void*)l,
                                   16, 0, 0);
}

// ---------------- LayerNorm (fp32 -> bf16) ----------------
__global__ __launch_bounds__(256)
void ln_kernel(const float* __restrict__ x, const float* __restrict__ gamma,
               const float* __restrict__ beta, unsigned short* __restrict__ h) {
  __shared__ float red[8];
  int row = blockIdx.x;          // 0..4095
  int t = threadIdx.x;           // 0..255, 4 floats each
  float4 v = reinterpret_cast<const float4*>(x + (size_t)row * 1024)[t];
  float s  = v.x + v.y + v.z + v.w;
  float sq = v.x*v.x + v.y*v.y + v.z*v.z + v.w*v.w;
#pragma unroll
  for (int off = 1; off < 64; off <<= 1) {
    s  += __shfl_xor(s, off);
    sq += __shfl_xor(sq, off);
  }
  int wid = t >> 6;
  if ((t & 63) == 0) { red[wid] = s; red[4 + wid] = sq; }
  __syncthreads();
  s  = red[0] + red[1] + red[2] + red[3];
  sq = red[4] + red[5] + red[6] + red[7];
  float mu   = s * (1.0f / 1024.0f);
  float var  = sq * (1.0f / 1024.0f) - mu * mu;
  float rstd = rsqrtf(var + 1e-5f);
  float4 g = reinterpret_cast<const float4*>(gamma)[t];
  float4 b = reinterpret_cast<const float4*>(beta)[t];
  ushort4 o;
  o.x = f2bf((v.x - mu) * rstd * g.x + b.x);
  o.y = f2bf((v.y - mu) * rstd * g.y + b.y);
  o.z = f2bf((v.z - mu) * rstd * g.z + b.z);
  o.w = f2bf((v.w - mu) * rstd * g.w + b.w);
  reinterpret_cast<ushort4*>(h + (size_t)row * 1024)[t] = o;
}

// ---------------- Transpose + cast: src fp32 [R,C] -> dst bf16 [C,R] ----------------
__global__ __launch_bounds__(256)
void transpose_cast_kernel(const float* __restrict__ src, unsigned short* __restrict__ dst,
                           int R, int C) {
  __shared__ float tile[32][33];
  int tx = threadIdx.x & 31, ty = threadIdx.x >> 5;  // 32 x 8
  int c0 = blockIdx.x * 32, r0 = blockIdx.y * 32;
#pragma unroll
  for (int i = 0; i < 4; i++)
    tile[ty + i * 8][tx] = src[(size_t)(r0 + ty + i * 8) * C + c0 + tx];
  __syncthreads();
#pragma unroll
  for (int i = 0; i < 4; i++) {
    int r = ty + i * 8;
    dst[(size_t)(c0 + r) * R + r0 + tx] = f2bf(tile[tx][r]);
  }
}

// ---------------- GEMM: C[M,N] = A[M,K] * Bt[N,K]^T (+epilogue) ----------------
// 128x128 tile, BK=64, 256 threads = 4 waves (2x2 of 64x64), 16x16x32 MFMA.
// LDS kb-major: chunk c = kb*128 + row holds 8 bf16 of row `row`, k-slice kb.
// MODE 0: qkv epilogue (bias, split q/k/vT, q scaled). MODE 1: bias+residual fp32 out.
template <int MODE>
__global__ __launch_bounds__(256)
void gemm128(const unsigned short* __restrict__ A,
             const unsigned short* __restrict__ Bt,
             int K,
             const float* __restrict__ bias,
             unsigned short* __restrict__ qdst, unsigned short* __restrict__ kdst,
             unsigned short* __restrict__ vTdst,
             const float* __restrict__ xres, float* __restrict__ out) {
  __shared__ unsigned short As[8192];  // 16 KB
  __shared__ unsigned short Bs[8192];
  int tid = threadIdx.x, wid = tid >> 6, lane = tid & 63;
  int l15 = lane & 15, l4 = lane >> 4;
  int brow = blockIdx.y * 128, bcol = blockIdx.x * 128;
  int wr = wid >> 1, wc = wid & 1;
  f32x4 acc[4][4] = {};

  for (int kt = 0; kt < K; kt += 64) {
    __syncthreads();
#pragma unroll
    for (int r = 0; r < 4; r++) {
      int c  = wid * 256 + r * 64;   // wave-uniform chunk base
      int cl = c + lane;
      int kb = cl >> 7, row = cl & 127;
      gload_lds16(A  + (size_t)(brow + row) * K + kt + kb * 8, As + c * 8);
      gload_lds16(Bt + (size_t)(bcol + row) * K + kt + kb * 8, Bs + c * 8);
    }
    __syncthreads();
#pragma unroll
    for (int ks = 0; ks < 2; ks++) {
      int kb = ks * 4 + l4;
      bf16x8 af[4], bfr[4];
#pragma unroll
      for (int m = 0; m < 4; m++)
        af[m] = *reinterpret_cast<const bf16x8*>(As + (kb * 128 + wr * 64 + m * 16 + l15) * 8);
#pragma unroll
      for (int n = 0; n < 4; n++)
        bfr[n] = *reinterpret_cast<const bf16x8*>(Bs + (kb * 128 + wc * 64 + n * 16 + l15) * 8);
#pragma unroll
      for (int m = 0; m < 4; m++)
#pragma unroll
        for (int n = 0; n < 4; n++)
          acc[m][n] = __builtin_amdgcn_mfma_f32_16x16x32_bf16(af[m], bfr[n], acc[m][n], 0, 0, 0);
    }
  }

  if (MODE == 0) {
    int sec = bcol >> 10;            // 0=q, 1=k, 2=v  (128-wide tiles never straddle)
    int secbase = sec << 10;
#pragma unroll
    for (int m = 0; m < 4; m++) {
      int row0 = brow + wr * 64 + m * 16 + l4 * 4;
      int b = row0 >> 11, t0 = row0 & 2047;
#pragma unroll
      for (int n = 0; n < 4; n++) {
        int col = (bcol & 1023) + wc * 64 + n * 16 + l15;
        float bv = bias[secbase + col];
        int hh = col >> 6, d = col & 63;
        if (sec == 2) {
          ushort4 pk;
          pk.x = f2bf(acc[m][n][0] + bv);
          pk.y = f2bf(acc[m][n][1] + bv);
          pk.z = f2bf(acc[m][n][2] + bv);
          pk.w = f2bf(acc[m][n][3] + bv);
          *reinterpret_cast<ushort4*>(vTdst + ((size_t)(b * 16 + hh) * 64 + d) * 2048 + t0) = pk;
        } else {
          unsigned short* dst = (sec == 0) ? qdst : kdst;
          // q pre-scaled by 1/sqrt(hd) * log2(e) so attention can use exp2
          float sc = (sec == 0) ? 0.125f * 1.44269504088896f : 1.0f;
#pragma unroll
          for (int j = 0; j < 4; j++)
            dst[((size_t)(b * 16 + hh) * 2048 + t0 + j) * 64 + d] = f2bf((acc[m][n][j] + bv) * sc);
        }
      }
    }
  } else {
#pragma unroll
    for (int m = 0; m < 4; m++) {
      int row0 = brow + wr * 64 + m * 16 + l4 * 4;
#pragma unroll
      for (int n = 0; n < 4; n++) {
        int col = bcol + wc * 64 + n * 16 + l15;
        float bv = bias[col];
#pragma unroll
        for (int j = 0; j < 4; j++) {
          size_t idx = (size_t)(row0 + j) * 1024 + col;
          out[idx] = acc[m][n][j] + bv + xres[idx];
        }
      }
    }
  }
}

// ---------------- Flash attention (swapped-operand, transposed PV) ----------------
// 512 blocks (XCD-chunked), 4 waves x 32 q-rows = 128 q-rows/block. KV tiles of 64.
// S^T = mfma(A=K, B=Q): lane owns q-row l15 (x2 m-blocks), 16 keys -> in-reg tree
// reduce + 2 shfl. O^T = mfma(A=V^T, B=P^T): V-frags read DIRECT from global vT
// (L2-resident, 256KB/head) - no V staging. K staged in LDS (dbuf, XOR-swizzled).
// P^T relayout via wave-private swizzled LDS (packed b64 writes, b128 reads).
__global__ __launch_bounds__(256, 2)
void attn_kernel(const unsigned short* __restrict__ q,
                 const unsigned short* __restrict__ kk,
                 const unsigned short* __restrict__ vT,
                 unsigned short* __restrict__ o) {
  const int T = 2048;
  __shared__ unsigned short Ks[2][4096];   // 16 KB: key(64) x d-chunk(8, ^key&7)
  __shared__ unsigned short Ps[4][2048];   // 16 KB: per-wave [q 32][key 64 ^ (q&7)<<3]
  int tid = threadIdx.x, wid = tid >> 6, lane = tid & 63;
  int l15 = lane & 15, l4 = lane >> 4;
  int swz = (l15 & 7) << 3;                // Ps XOR swizzle for this lane's q-row

  // XCD-chunked bijective remap: all 16 q-blocks of a head land on one XCD
  int lin = blockIdx.x;                    // 0..511
  int rl  = (lin & 7) * 64 + (lin >> 3);
  int bx = rl & 15, bh = rl >> 4;
  int q0 = bx * 128 + wid * 32;            // wave's 32 q-rows

  const unsigned short* qh = q  + (size_t)bh * T * 64;
  const unsigned short* kh = kk + (size_t)bh * T * 64;
  const unsigned short* vh = vT + (size_t)bh * 64 * T;

  // Q B-fragments: lane holds Q[q = q0 + m*16 + l15][d = ks*32 + l4*8 ..+8]
  bf16x8 qf[2][2];
#pragma unroll
  for (int m = 0; m < 2; m++)
#pragma unroll
    for (int ks = 0; ks < 2; ks++)
      qf[m][ks] = *reinterpret_cast<const bf16x8*>(
          qh + (size_t)(q0 + m * 16 + l15) * 64 + ks * 32 + l4 * 8);

  f32x4 accO[2][4] = {};                   // O^T[d = n*16+l4*4+j][q = l15 + 16m]
  float mst[2] = {-1e30f, -1e30f}, lst[2] = {0.0f, 0.0f};

#define STAGE(buf, kv0)                                                        \
  {                                                                            \
    _Pragma("unroll") for (int r = 0; r < 2; r++) {                            \
      int c  = wid * 128 + r * 64;                                             \
      int sl = c + lane;                                                       \
      int key = sl >> 3;                                                       \
      int kb  = (sl & 7) ^ (key & 7);                                          \
      gload_lds16(kh + (size_t)((kv0) + key) * 64 + kb * 8, &Ks[buf][c * 8]);  \
    }                                                                          \
  }

  STAGE(0, 0);
  __syncthreads();
  int cur = 0;

  for (int kv0 = 0; kv0 < T; kv0 += 64) {
    // V A-fragments direct from global (L2): V^T[d = n*16+l15][key = ks*32+l4*8 ..+8]
    // issued FIRST so their vmcnt-wait (at PV) doesn't force draining the K-prefetch
    bf16x8 vf[2][4];
#pragma unroll
    for (int ks = 0; ks < 2; ks++)
#pragma unroll
      for (int n = 0; n < 4; n++)
        vf[ks][n] = *reinterpret_cast<const bf16x8*>(
            vh + (size_t)(n * 16 + l15) * T + kv0 + ks * 32 + l4 * 8);

    if (kv0 + 64 < T) STAGE(cur ^ 1, kv0 + 64);

    // S^T = K Q^T: lane holds S^T[key = n*16 + l4*4 + j][q = l15 + 16m]
    f32x4 s[2][4] = {};
#pragma unroll
    for (int ks = 0; ks < 2; ks++) {
#pragma unroll
      for (int n = 0; n < 4; n++) {
        int slot = (n * 16 + l15) * 8 + ((ks * 4 + l4) ^ (l15 & 7));
        bf16x8 kf = *reinterpret_cast<const bf16x8*>(&Ks[cur][slot * 8]);
#pragma unroll
        for (int m = 0; m < 2; m++)
          s[m][n] = __builtin_amdgcn_mfma_f32_16x16x32_bf16(kf, qf[m][ks], s[m][n], 0, 0, 0);
      }
    }

    // online softmax: lane owns 16 of 64 key-scores for q-row l15 (per m)
#pragma unroll
    for (int m = 0; m < 2; m++) {
      float mx01 = fmaxf(fmaxf(s[m][0][0], s[m][0][1]), fmaxf(s[m][0][2], s[m][0][3]));
      float mx11 = fmaxf(fmaxf(s[m][1][0], s[m][1][1]), fmaxf(s[m][1][2], s[m][1][3]));
      float mx21 = fmaxf(fmaxf(s[m][2][0], s[m][2][1]), fmaxf(s[m][2][2], s[m][2][3]));
      float mx31 = fmaxf(fmaxf(s[m][3][0], s[m][3][1]), fmaxf(s[m][3][2], s[m][3][3]));
      float mx = fmaxf(fmaxf(mx01, mx11), fmaxf(mx21, mx31));
      mx = fmaxf(mx, __shfl_xor(mx, 16));
      mx = fmaxf(mx, __shfl_xor(mx, 32));
      float mnew = fmaxf(mst[m], mx);
      float a = fast_exp2(mst[m] - mnew);
      float sum = 0.0f;
#pragma unroll
      for (int n = 0; n < 4; n++) {
        unsigned int u0, u1;
#pragma unroll
        for (int j = 0; j < 4; j++) {
          float p = fast_exp2(s[m][n][j] - mnew);
          s[m][n][j] = p;
          sum += p;
        }
        u0 = bfbits(s[m][n][0]) | (bfbits(s[m][n][1]) << 16);
        u1 = bfbits(s[m][n][2]) | (bfbits(s[m][n][3]) << 16);
        // P^T[key = n*16+l4*4 ..+4][q-row] -> Ps[q][key^swz], packed 8B
        *reinterpret_cast<uint2*>(
            &Ps[wid][(m * 16 + l15) * 64 + ((n * 16 + l4 * 4) ^ swz)]) =
            make_uint2(u0, u1);
      }
      sum += __shfl_xor(sum, 16);
      sum += __shfl_xor(sum, 32);
      lst[m] = lst[m] * a + sum;
      mst[m] = mnew;
#pragma unroll
      for (int n = 0; n < 4; n++)
#pragma unroll
        for (int j = 0; j < 4; j++) accO[m][n][j] *= a;
    }

    // O^T += V^T P^T : B-frag = P^T[key = ks*32+l4*8 ..+8][q = l15+16m]
#pragma unroll
    for (int ks = 0; ks < 2; ks++) {
#pragma unroll
      for (int m = 0; m < 2; m++) {
        bf16x8 pf = *reinterpret_cast<const bf16x8*>(
            &Ps[wid][(m * 16 + l15) * 64 + ((ks * 32 + l4 * 8) ^ swz)]);
#pragma unroll
        for (int n = 0; n < 4; n++)
          accO[m][n] = __builtin_amdgcn_mfma_f32_16x16x32_bf16(vf[ks][n], pf, accO[m][n], 0, 0, 0);
      }
    }

    __syncthreads();
    cur ^= 1;
  }
#undef STAGE

  int b = bh >> 4, hh = bh & 15;
#pragma unroll
  for (int m = 0; m < 2; m++) {
    float inv = 1.0f / lst[m];
    int row = q0 + m * 16 + l15;
#pragma unroll
    for (int n = 0; n < 4; n++) {
      ushort4 pk;
      pk.x = f2bf(accO[m][n][0] * inv);
      pk.y = f2bf(accO[m][n][1] * inv);
      pk.z = f2bf(accO[m][n][2] * inv);
      pk.w = f2bf(accO[m][n][3] * inv);
      *reinterpret_cast<ushort4*>(
          &o[(size_t)(b * 2048 + row) * 1024 + hh * 64 + n * 16 + l4 * 4]) = pk;
    }
  }
}

extern "C" void kernel_launch(void* const* d_in, const int* in_sizes, int n_in,
                              void* d_out, int out_size, void* d_ws, size_t ws_size,
                              hipStream_t stream) {
  const float* x     = (const float*)d_in[0];
  const float* W_qkv = (const float*)d_in[1];
  const float* b_qkv = (const float*)d_in[2];
  const float* W_out = (const float*)d_in[3];
  const float* b_out = (const float*)d_in[4];
  const float* gamma = (const float*)d_in[5];
  const float* beta  = (const float*)d_in[6];
  float* out = (float*)d_out;

  char* ws = (char*)d_ws;
  unsigned short* h     = (unsigned short*)(ws);
  unsigned short* WqkvT = (unsigned short*)(ws + (size_t)(8)  * 1024 * 1024);
  unsigned short* WoutT = (unsigned short*)(ws + (size_t)(14) * 1024 * 1024);
  unsigned short* qb    = (unsigned short*)(ws + (size_t)(16) * 1024 * 1024);
  unsigned short* kb    = (unsigned short*)(ws + (size_t)(24) * 1024 * 1024);
  unsigned short* vTb   = (unsigned short*)(ws + (size_t)(32) * 1024 * 1024);
  unsigned short* attno = (unsigned short*)(ws + (size_t)(40) * 1024 * 1024);

  ln_kernel<<<4096, 256, 0, stream>>>(x, gamma, beta, h);
  transpose_cast_kernel<<<dim3(96, 32), 256, 0, stream>>>(W_qkv, WqkvT, 1024, 3072);
  transpose_cast_kernel<<<dim3(32, 32), 256, 0, stream>>>(W_out, WoutT, 1024, 1024);
  gemm128<0><<<dim3(24, 32), 256, 0, stream>>>(h, WqkvT, 1024, b_qkv, qb, kb, vTb, nullptr, nullptr);
  attn_kernel<<<512, 256, 0, stream>>>(qb, kb, vTb, attno);
  gemm128<1><<<dim3(8, 32), 256, 0, stream>>>(attno, WoutT, 1024, b_out, nullptr, nullptr, nullptr, x, out);
}